// Round 1
// baseline (2941.431 us; speedup 1.0000x reference)
//
#include <hip/hip_runtime.h>
#include <math.h>

#define EPSF 1e-7f

// ============================================================================
// conv1: x[1024,3,32,32] -> h1[1024,128,15,15], 3x3 stride2, ReLU
// block = (image, 32-oc tile); thread = one output position (225 active of 256)
// input window held in registers, weights read via wave-uniform index (s_load)
// ============================================================================
__global__ __launch_bounds__(256) void conv1_kernel(
    const float* __restrict__ x, const float* __restrict__ w,
    const float* __restrict__ bias, float* __restrict__ out)
{
  const int b   = blockIdx.x;
  const int oc0 = blockIdx.y * 32;
  const int t   = threadIdx.x;
  if (t >= 225) return;
  const int py = t / 15, px = t % 15;
  const float* xb = x + b * 3072;
  float win[27];
#pragma unroll
  for (int c = 0; c < 3; ++c)
#pragma unroll
    for (int ky = 0; ky < 3; ++ky)
#pragma unroll
      for (int kx = 0; kx < 3; ++kx)
        win[c*9 + ky*3 + kx] = xb[c*1024 + (py*2 + ky)*32 + (px*2 + kx)];
  for (int oc = 0; oc < 32; ++oc) {
    const float* wp = w + (oc0 + oc) * 27;   // oc uniform -> scalar loads
    float acc = bias[oc0 + oc];
#pragma unroll
    for (int q = 0; q < 27; ++q) acc = fmaf(win[q], wp[q], acc);
    out[(b*128 + oc0 + oc)*225 + t] = fmaxf(acc, 0.f);
  }
}

// ============================================================================
// conv2: h1[1024,128,15,15] -> h2[1024,256,6,6], 5x5 stride2, ReLU  (dominant)
// block = (image, 128-oc tile), 192 threads = 32 oc-groups(4 oc) x 6 out rows
// LDS: weights [4ic][25tap][128oc pad132] 52.8KB + input [4ic][15][16] 3.8KB
// inner: per (ic,ky): 4x b128 input row -> regs, 5x b128 weights, 120 FMA
// ============================================================================
__global__ __launch_bounds__(192) void conv2_kernel(
    const float* __restrict__ in, const float* __restrict__ w,
    const float* __restrict__ bias, float* __restrict__ out)
{
  __shared__ float Wl[4*25*132];   // stride 132: b128-aligned, banks shift by 4
  __shared__ float Il[4*15*16];    // rows padded to 16 floats for b128
  const int b   = blockIdx.x;
  const int oc0 = blockIdx.y * 128;
  const int t   = threadIdx.x;
  const int ocg = t & 31;          // 4 consecutive oc: ocg*4
  const int row = t >> 5;          // output row 0..5
  float acc[4][6];
#pragma unroll
  for (int c = 0; c < 4; ++c)
#pragma unroll
    for (int p = 0; p < 6; ++p) acc[c][p] = 0.f;
  const float* inb = in + b * 128*225;
  for (int ic0 = 0; ic0 < 128; ic0 += 4) {
    __syncthreads();
    for (int i = t; i < 900; i += 192) {
      int ic = i / 225, pix = i % 225;
      Il[(ic*15 + pix/15)*16 + pix%15] = inb[(ic0 + ic)*225 + pix];
    }
    for (int i = t; i < 12800; i += 192) {
      int oc = i / 100, r = i % 100;
      int ic = r / 25, tap = r % 25;
      Wl[(ic*25 + tap)*132 + oc] = w[((oc0 + oc)*128 + ic0 + ic)*25 + tap];
    }
    __syncthreads();
#pragma unroll
    for (int ic = 0; ic < 4; ++ic) {
#pragma unroll
      for (int ky = 0; ky < 5; ++ky) {
        const int iy = row*2 + ky;                  // <= 14
        const float* ir = &Il[(ic*15 + iy)*16];
        float4 r0 = *(const float4*)&ir[0];
        float4 r1 = *(const float4*)&ir[4];
        float4 r2 = *(const float4*)&ir[8];
        float4 r3 = *(const float4*)&ir[12];        // elt 15 = pad, never used
        float rr[16] = {r0.x,r0.y,r0.z,r0.w, r1.x,r1.y,r1.z,r1.w,
                        r2.x,r2.y,r2.z,r2.w, r3.x,r3.y,r3.z,r3.w};
#pragma unroll
        for (int kx = 0; kx < 5; ++kx) {
          float4 wv = *(const float4*)&Wl[(ic*25 + ky*5 + kx)*132 + ocg*4];
#pragma unroll
          for (int p = 0; p < 6; ++p) {
            float iv = rr[p*2 + kx];
            acc[0][p] = fmaf(wv.x, iv, acc[0][p]);
            acc[1][p] = fmaf(wv.y, iv, acc[1][p]);
            acc[2][p] = fmaf(wv.z, iv, acc[2][p]);
            acc[3][p] = fmaf(wv.w, iv, acc[3][p]);
          }
        }
      }
    }
  }
#pragma unroll
  for (int c = 0; c < 4; ++c) {
    const int oc = oc0 + ocg*4 + c;
    const float bv = bias[oc];
#pragma unroll
    for (int p = 0; p < 6; ++p)
      out[(b*256 + oc)*36 + row*6 + p] = fmaxf(acc[c][p] + bv, 0.f);
  }
}

// ============================================================================
// conv3: h2[1024,256,6,6] -> h3[1024,256,2,2], 5x5 stride1, ReLU
// block = (16-image tile, 64-oc tile), 256 thr = 16 img x 16 oc-groups(4 oc)
// LDS: input [16img][4ic][6][8] 12.3KB + weights [4ic][25][64oc pad68] 27.2KB
// ============================================================================
__global__ __launch_bounds__(256) void conv3_kernel(
    const float* __restrict__ in, const float* __restrict__ w,
    const float* __restrict__ bias, float* __restrict__ out)
{
  __shared__ float Wl[4*25*68];
  __shared__ float Il[16*4*6*8];
  const int b0  = blockIdx.x * 16;
  const int oc0 = blockIdx.y * 64;
  const int t   = threadIdx.x;
  const int og  = t & 15;     // 4 oc: og*4
  const int ig  = t >> 4;     // image within tile
  float acc[4][4];
#pragma unroll
  for (int c = 0; c < 4; ++c)
#pragma unroll
    for (int p = 0; p < 4; ++p) acc[c][p] = 0.f;
  for (int ic0 = 0; ic0 < 256; ic0 += 4) {
    __syncthreads();
    for (int i = t; i < 2304; i += 256) {
      int img = i / 144, r = i % 144;
      int ic = r / 36, pix = r % 36;
      Il[((img*4 + ic)*6 + pix/6)*8 + pix%6] = in[((b0 + img)*256 + ic0 + ic)*36 + pix];
    }
    for (int i = t; i < 6400; i += 256) {
      int oc = i / 100, r = i % 100;
      int ic = r / 25, tap = r % 25;
      Wl[(ic*25 + tap)*68 + oc] = w[((oc0 + oc)*256 + ic0 + ic)*25 + tap];
    }
    __syncthreads();
#pragma unroll
    for (int ic = 0; ic < 4; ++ic) {
      const float* Ib = &Il[(ig*4 + ic)*48];
#pragma unroll
      for (int ky = 0; ky < 5; ++ky) {
        float4 a0 = *(const float4*)&Ib[ky*8];
        float4 a1 = *(const float4*)&Ib[ky*8 + 4];
        float4 c0 = *(const float4*)&Ib[(ky+1)*8];
        float4 c1 = *(const float4*)&Ib[(ky+1)*8 + 4];
        float ra[8] = {a0.x,a0.y,a0.z,a0.w,a1.x,a1.y,a1.z,a1.w};
        float rb[8] = {c0.x,c0.y,c0.z,c0.w,c1.x,c1.y,c1.z,c1.w};
#pragma unroll
        for (int kx = 0; kx < 5; ++kx) {
          float4 wv = *(const float4*)&Wl[(ic*25 + ky*5 + kx)*68 + og*4];
          float wc[4] = {wv.x, wv.y, wv.z, wv.w};
#pragma unroll
          for (int c = 0; c < 4; ++c) {
            acc[c][0] = fmaf(wc[c], ra[kx],   acc[c][0]);   // (py0,px0)
            acc[c][1] = fmaf(wc[c], ra[kx+1], acc[c][1]);   // (py0,px1)
            acc[c][2] = fmaf(wc[c], rb[kx],   acc[c][2]);   // (py1,px0)
            acc[c][3] = fmaf(wc[c], rb[kx+1], acc[c][3]);   // (py1,px1)
          }
        }
      }
    }
  }
#pragma unroll
  for (int c = 0; c < 4; ++c) {
    const int oc = oc0 + og*4 + c;
    const float bv = bias[oc];
#pragma unroll
    for (int p = 0; p < 4; ++p)
      out[((b0 + ig)*256 + oc)*4 + p] = fmaxf(acc[c][p] + bv, 0.f);
  }
}

// ============================================================================
// caps: squash -> u_hat -> 3x dynamic routing -> v_lengths + fused fc1
// one block per image, 256 threads. one-hot mask means fc1 only needs the
// 16 columns of fc1_w at y*16 -> fc1 is 512x16 per image, fused here.
// ============================================================================
__global__ __launch_bounds__(256) void caps_kernel(
    const float* __restrict__ h3, const float* __restrict__ cw,
    const float* __restrict__ cb, const int* __restrict__ y,
    const float* __restrict__ fc1w, const float* __restrict__ fc1b,
    float* __restrict__ vlen, float* __restrict__ h1f)
{
  __shared__ float prim[1024];     // [64][16]
  __shared__ float uh[10240];      // [64][10][16]
  __shared__ float bij[640];
  __shared__ float cij[640];
  __shared__ float vv[160];        // [10][16]
  const int b = blockIdx.x, t = threadIdx.x;
  // --- primary caps squash ---
  {
    const int cap = t >> 2, part = t & 3;
    float4 h = *(const float4*)&h3[b*1024 + cap*16 + part*4];
    float d = h.x*h.x + h.y*h.y + h.z*h.z + h.w*h.w;
    d += __shfl_xor(d, 1);
    d += __shfl_xor(d, 2);
    float sc = d / (1.f + d) / sqrtf(d + EPSF);
    float4 o4 = make_float4(h.x*sc, h.y*sc, h.z*sc, h.w*sc);
    *(float4*)&prim[cap*16 + part*4] = o4;
  }
  for (int f = t; f < 640; f += 256) bij[f] = 0.f;
  __syncthreads();
  // --- u_hat[i][o][j] = sum_k prim[i][k] * cw[i][o][k][j] ---
  for (int f = t; f < 10240; f += 256) {
    int i = f / 160, r = f % 160;
    int o = r >> 4, j = r & 15;
    const float* wp = cw + i*2560 + o*256 + j;   // k-stride 16
    const float* pp = prim + i*16;
    float s = 0.f;
#pragma unroll
    for (int k = 0; k < 16; ++k) s = fmaf(pp[k], wp[k*16], s);
    uh[f] = s;
  }
  __syncthreads();
  // --- routing (3 iters; u_hat == u_hat_det in forward values) ---
  for (int r = 0; r < 3; ++r) {
    if (t < 64) {
      float e[10];
      float mx = -1e30f;
#pragma unroll
      for (int o = 0; o < 10; ++o) { e[o] = bij[t*10 + o]; mx = fmaxf(mx, e[o]); }
      float sum = 0.f;
#pragma unroll
      for (int o = 0; o < 10; ++o) { e[o] = expf(e[o] - mx); sum += e[o]; }
      float inv = 1.f / sum;
#pragma unroll
      for (int o = 0; o < 10; ++o) cij[t*10 + o] = e[o] * inv;
    }
    __syncthreads();
    if (t < 160) {                 // t = o*16 + j, 16-lane groups wave-aligned
      const int o = t >> 4;
      float s = cb[t];
      for (int i = 0; i < 64; ++i) s = fmaf(cij[i*10 + o], uh[i*160 + t], s);
      float d = s*s;
      d += __shfl_xor(d, 1); d += __shfl_xor(d, 2);
      d += __shfl_xor(d, 4); d += __shfl_xor(d, 8);
      float sc = d / (1.f + d) / sqrtf(d + EPSF);
      vv[t] = s * sc;
      if (r == 2 && (t & 15) == 0)
        vlen[b*10 + o] = sqrtf(sc*sc*d + EPSF);  // sum v^2 = sc^2 * d
    }
    __syncthreads();
    if (r < 2) {
      for (int f = t; f < 640; f += 256) {
        int i = f / 10, o = f % 10;
        const float* up = &uh[i*160 + o*16];
        const float* vp = &vv[o*16];
        float a = 0.f;
#pragma unroll
        for (int j = 0; j < 16; ++j) a = fmaf(up[j], vp[j], a);
        bij[f] += a;
      }
      __syncthreads();
    }
  }
  // --- fused fc1 on masked capsule ---
  const int yb = y[b];
  const float* vy = &vv[yb*16];
  for (int n = t; n < 512; n += 256) {
    const float* wr = fc1w + n*160 + yb*16;
    float s = fc1b[n];
#pragma unroll
    for (int k = 0; k < 16; ++k) s = fmaf(vy[k], wr[k], s);
    h1f[b*512 + n] = fmaxf(s, 0.f);
  }
}

// ============================================================================
// fc: out[M,N] = act(A[M,K] @ W[N,K]^T + bias). BM=64 BN=128 BK=16, 4x8/thread
// ACT: 0 = relu, 1 = sigmoid
// ============================================================================
template<int ACT>
__global__ __launch_bounds__(256) void fc_kernel(
    const float* __restrict__ A, const float* __restrict__ W,
    const float* __restrict__ bias, float* __restrict__ out,
    int M, int N, int K)
{
  __shared__ float Al[16*68];    // [k][m] pad 68
  __shared__ float Bl[16*132];   // [k][n] pad 132
  const int m0 = blockIdx.x * 64;
  const int n0 = blockIdx.y * 128;
  const int t  = threadIdx.x;
  const int tx = t & 15;   // 8 n
  const int ty = t >> 4;   // 4 m
  float acc[4][8];
#pragma unroll
  for (int i2 = 0; i2 < 4; ++i2)
#pragma unroll
    for (int j2 = 0; j2 < 8; ++j2) acc[i2][j2] = 0.f;
  for (int k0 = 0; k0 < K; k0 += 16) {
    __syncthreads();
    {
      int m = t >> 2, kq = (t & 3) * 4;
      float4 v = *(const float4*)&A[(m0 + m)*K + k0 + kq];
      Al[(kq+0)*68 + m] = v.x;
      Al[(kq+1)*68 + m] = v.y;
      Al[(kq+2)*68 + m] = v.z;
      Al[(kq+3)*68 + m] = v.w;
    }
    for (int f = t; f < 512; f += 256) {
      int n = f >> 2, kq = (f & 3) * 4;
      float4 v = *(const float4*)&W[(n0 + n)*K + k0 + kq];
      Bl[(kq+0)*132 + n] = v.x;
      Bl[(kq+1)*132 + n] = v.y;
      Bl[(kq+2)*132 + n] = v.z;
      Bl[(kq+3)*132 + n] = v.w;
    }
    __syncthreads();
#pragma unroll
    for (int kk = 0; kk < 16; ++kk) {
      float4 a  = *(const float4*)&Al[kk*68 + ty*4];
      float4 b0 = *(const float4*)&Bl[kk*132 + tx*8];
      float4 b1 = *(const float4*)&Bl[kk*132 + tx*8 + 4];
      float am[4] = {a.x, a.y, a.z, a.w};
      float bn[8] = {b0.x, b0.y, b0.z, b0.w, b1.x, b1.y, b1.z, b1.w};
#pragma unroll
      for (int i2 = 0; i2 < 4; ++i2)
#pragma unroll
        for (int j2 = 0; j2 < 8; ++j2)
          acc[i2][j2] = fmaf(am[i2], bn[j2], acc[i2][j2]);
    }
  }
#pragma unroll
  for (int i2 = 0; i2 < 4; ++i2) {
    const int m = m0 + ty*4 + i2;
#pragma unroll
    for (int j2 = 0; j2 < 8; ++j2) {
      const int n = n0 + tx*8 + j2;
      float v = acc[i2][j2] + bias[n];
      if (ACT == 0) v = fmaxf(v, 0.f);
      else          v = 1.f / (1.f + expf(-v));
      out[m*N + n] = v;
    }
  }
}

// ============================================================================
extern "C" void kernel_launch(void* const* d_in, const int* in_sizes, int n_in,
                              void* d_out, int out_size, void* d_ws, size_t ws_size,
                              hipStream_t stream) {
  const float* x       = (const float*)d_in[0];
  const int*   y       = (const int*)  d_in[1];
  const float* conv1_w = (const float*)d_in[2];
  const float* conv1_b = (const float*)d_in[3];
  const float* conv2_w = (const float*)d_in[4];
  const float* conv2_b = (const float*)d_in[5];
  const float* conv3_w = (const float*)d_in[6];
  const float* conv3_b = (const float*)d_in[7];
  const float* caps_w  = (const float*)d_in[8];
  const float* caps_b  = (const float*)d_in[9];
  const float* fc1_w   = (const float*)d_in[10];
  const float* fc1_b   = (const float*)d_in[11];
  const float* fc2_w   = (const float*)d_in[12];
  const float* fc2_b   = (const float*)d_in[13];
  const float* fc3_w   = (const float*)d_in[14];
  const float* fc3_b   = (const float*)d_in[15];
  float* out = (float*)d_out;
  float* ws  = (float*)d_ws;

  // ws layout (floats): total 41,549,824 = 166.2 MB
  float* h1c = ws;                  // conv1 out: 1024*128*225 = 29,491,200
  float* h2c = h1c + 29491200;      // conv2 out: 1024*256*36  =  9,437,184
  float* h3c = h2c + 9437184;       // conv3 out: 1024*1024    =  1,048,576
  float* h1f = h3c + 1048576;       // fc1 out:   1024*512     =    524,288
  float* h2f = h1f + 524288;        // fc2 out:   1024*1024    =  1,048,576

  conv1_kernel<<<dim3(1024, 4), 256, 0, stream>>>(x, conv1_w, conv1_b, h1c);
  conv2_kernel<<<dim3(1024, 2), 192, 0, stream>>>(h1c, conv2_w, conv2_b, h2c);
  conv3_kernel<<<dim3(64, 4),   256, 0, stream>>>(h2c, conv3_w, conv3_b, h3c);
  caps_kernel<<<dim3(1024),     256, 0, stream>>>(h3c, caps_w, caps_b, y,
                                                  fc1_w, fc1_b, out, h1f);
  fc_kernel<0><<<dim3(16, 8),  256, 0, stream>>>(h1f, fc2_w, fc2_b, h2f,
                                                 1024, 1024, 512);
  fc_kernel<1><<<dim3(16, 24), 256, 0, stream>>>(h2f, fc3_w, fc3_b, out + 10240,
                                                 1024, 3072, 1024);
}

// Round 2
// 1111.421 us; speedup vs baseline: 2.6465x; 2.6465x over previous
//
#include <hip/hip_runtime.h>
#include <hip/hip_bf16.h>
#include <math.h>

#define EPSF 1e-7f

typedef __attribute__((ext_vector_type(8))) short bhalf8;   // 8 bf16 (4 VGPRs)
typedef __attribute__((ext_vector_type(4))) float floatx4;  // MFMA acc

__device__ __forceinline__ void gload_lds16(const void* g, void* l) {
  __builtin_amdgcn_global_load_lds(
      (const __attribute__((address_space(1))) unsigned int*)g,
      (__attribute__((address_space(3))) unsigned int*)l,
      16, 0, 0);
}

// ============================================================================
// conv1: x[1024,3,32,32] -> h1t[1024,225,128] bf16 (position-major, ic inner)
// 3x3 stride2, ReLU. block = (image, 32-oc tile); thread = one output position
// ============================================================================
__global__ __launch_bounds__(256) void conv1_kernel(
    const float* __restrict__ x, const float* __restrict__ w,
    const float* __restrict__ bias, __hip_bfloat16* __restrict__ out)
{
  const int b   = blockIdx.x;
  const int oc0 = blockIdx.y * 32;
  const int t   = threadIdx.x;
  if (t >= 225) return;
  const int py = t / 15, px = t % 15;
  const float* xb = x + b * 3072;
  float win[27];
#pragma unroll
  for (int c = 0; c < 3; ++c)
#pragma unroll
    for (int ky = 0; ky < 3; ++ky)
#pragma unroll
      for (int kx = 0; kx < 3; ++kx)
        win[c*9 + ky*3 + kx] = xb[c*1024 + (py*2 + ky)*32 + (px*2 + kx)];
  __hip_bfloat16 hv[32];
  for (int oc = 0; oc < 32; ++oc) {
    const float* wp = w + (oc0 + oc) * 27;   // oc uniform -> scalar loads
    float acc = bias[oc0 + oc];
#pragma unroll
    for (int q = 0; q < 27; ++q) acc = fmaf(win[q], wp[q], acc);
    hv[oc] = __float2bfloat16(fmaxf(acc, 0.f));
  }
  uint4* dst = (uint4*)&out[((size_t)b*225 + t)*128 + oc0];
  const uint4* src = (const uint4*)hv;
#pragma unroll
  for (int q = 0; q < 4; ++q) dst[q] = src[q];
}

// ============================================================================
// wtrans: conv2_w fp32 [oc][ic][5][5] -> Wt bf16 [oc][k], k = tap*128 + ic
// (so B-fragments see 8 contiguous k at fixed oc)
// ============================================================================
__global__ __launch_bounds__(256) void wtrans_kernel(
    const float* __restrict__ w, __hip_bfloat16* __restrict__ wt)
{
  int i = blockIdx.x*256 + threadIdx.x;          // 819,200 total
  int oc = i / 3200, r = i - oc*3200;
  int tap = r >> 7, ic = r & 127;
  wt[i] = __float2bfloat16(w[(oc*128 + ic)*25 + tap]);
}

// ============================================================================
// conv2_mfma: h1t[1024,225,128]bf16 -> h2[1024,256,36]fp32, 5x5 s2, ReLU
// GEMM view: M=(img,pos) 72/block, N=oc 256, K=tap*128+ic 3200.
// block = 2 images, 256 thr = 4 waves; wave w: 5 Mtiles x 4 Ntiles (oc w*64..)
// LDS: Il[2img][225pix][136pad] bf16 (input-stationary, staged once),
//      Bl 2 x 16KB double-buffered weight K-slices via global_load_lds w=16,
//      slot swizzle: slot = oc*4 + (kq ^ ((oc>>1)&3)) -> 2-way(free) B reads.
// one barrier per K-step (m97 pattern); A never needs a barrier after stage.
// ============================================================================
__global__ __launch_bounds__(256) void conv2_mfma_kernel(
    const __hip_bfloat16* __restrict__ a,   // h1t
    const __hip_bfloat16* __restrict__ wt,  // Wt [256][3200]
    const float* __restrict__ bias,
    float* __restrict__ out)
{
  __shared__ __align__(16) unsigned short Il[2*225*136];  // 122,400 B
  __shared__ uint4 Bl[2048];                              //  32,768 B
  const int b0   = blockIdx.x * 2;
  const int t    = threadIdx.x;
  const int lane = t & 63;
  const int w    = t >> 6;
  const int n    = lane & 15;
  const int g    = lane >> 4;

  // ---- stage both input images: global [pix][128ic] -> LDS [pix][136] ----
  for (int i = t; i < 7200; i += 256) {
    int img = (i >= 3600);
    int r = i - img*3600;
    int p = r >> 4, c = r & 15;
    uint4 v = *(const uint4*)((const char*)a +
              (((size_t)(b0+img)*225 + p)*256 + c*16));
    *(uint4*)((char*)Il + ((img*225 + p)*136 + c*8)*2) = v;
  }

  // ---- B staging: per-lane const global offset; 4 x 1KB issues per wave ----
  const int oc_l = lane >> 2;                        // oc within 16-row group
  const int kq_l = (lane & 3) ^ ((lane >> 3) & 3);   // swizzle inverse
  const char* gB = (const char*)wt +
                   (size_t)(w*64 + oc_l)*6400 + kq_l*16;
  char* BlBase = (char*)Bl;
#pragma unroll
  for (int jj = 0; jj < 4; ++jj)                     // step 0 -> buf 0
    gload_lds16(gB + (size_t)jj*16*6400, BlBase + (w*4 + jj)*1024);
  gB += 64;

  // ---- per-lane fragment base addresses ----
  int Abase[5];
#pragma unroll
  for (int mt = 0; mt < 5; ++mt) {
    int m  = mt*16 + n;
    int mm = (m < 72) ? m : 0;          // pad lanes read img0/pos0 (unused)
    int img = (mm >= 36);
    int pos = mm - img*36;
    int py = pos / 6, px = pos - py*6;
    Abase[mt] = ((img*225 + (2*py)*15 + 2*px)*136 + g*8) * 2;   // bytes
  }
  int Bbase[4];
#pragma unroll
  for (int nt = 0; nt < 4; ++nt) {
    int oc = w*64 + nt*16 + n;
    Bbase[nt] = (oc*4 + (g ^ ((n >> 1) & 3))) * 16;             // bytes
  }

  floatx4 acc[5][4];
#pragma unroll
  for (int mt = 0; mt < 5; ++mt)
#pragma unroll
    for (int nt = 0; nt < 4; ++nt)
      acc[mt][nt] = (floatx4){0.f, 0.f, 0.f, 0.f};

  __syncthreads();   // Il staged + buf0 loaded (vmcnt/lgkmcnt drained)

  int s = 0;
#pragma unroll 1
  for (int ky = 0; ky < 5; ++ky) {
#pragma unroll 1
    for (int kx = 0; kx < 5; ++kx) {
      const int tapoff = (ky*15 + kx) * 272;   // pixel offset in bytes
#pragma unroll
      for (int icq = 0; icq < 4; ++icq, ++s) {
        const int par = s & 1;
        if (s < 99) {                          // prefetch step s+1 -> buf^1
          char* dstb = BlBase + ((s+1)&1)*16384 + w*4096;
#pragma unroll
          for (int jj = 0; jj < 4; ++jj)
            gload_lds16(gB + (size_t)jj*16*6400, dstb + jj*1024);
          gB += 64;
        }
        bhalf8 bf[4];
        const char* bp = BlBase + par*16384;
#pragma unroll
        for (int nt = 0; nt < 4; ++nt)
          bf[nt] = *(const bhalf8*)(bp + Bbase[nt]);
#pragma unroll
        for (int mt = 0; mt < 5; ++mt) {
          bhalf8 af = *(const bhalf8*)((const char*)Il +
                       Abase[mt] + tapoff + icq*64);
#pragma unroll
          for (int nt = 0; nt < 4; ++nt)
            acc[mt][nt] = __builtin_amdgcn_mfma_f32_16x16x32_bf16(
                af, bf[nt], acc[mt][nt], 0, 0, 0);
        }
        __syncthreads();
      }
    }
  }

  // ---- epilogue: D row = g*4+reg, col = n(oc). write original layout ----
  float bv[4];
#pragma unroll
  for (int nt = 0; nt < 4; ++nt) bv[nt] = bias[w*64 + nt*16 + n];
#pragma unroll
  for (int mt = 0; mt < 5; ++mt) {
#pragma unroll
    for (int r = 0; r < 4; ++r) {
      int m = mt*16 + g*4 + r;
      if (m < 72) {
        int img = (m >= 36);
        int pos = m - img*36;
        float* op = out + ((size_t)(b0+img)*256 + w*64 + n)*36 + pos;
#pragma unroll
        for (int nt = 0; nt < 4; ++nt)
          op[nt*576] = fmaxf(acc[mt][nt][r] + bv[nt], 0.f);   // 16 oc * 36
      }
    }
  }
}

// ============================================================================
// conv3: h2[1024,256,6,6] -> h3[1024,256,2,2], 5x5 stride1, ReLU (unchanged)
// ============================================================================
__global__ __launch_bounds__(256) void conv3_kernel(
    const float* __restrict__ in, const float* __restrict__ w,
    const float* __restrict__ bias, float* __restrict__ out)
{
  __shared__ float Wl[4*25*68];
  __shared__ float Il[16*4*6*8];
  const int b0  = blockIdx.x * 16;
  const int oc0 = blockIdx.y * 64;
  const int t   = threadIdx.x;
  const int og  = t & 15;     // 4 oc: og*4
  const int ig  = t >> 4;     // image within tile
  float acc[4][4];
#pragma unroll
  for (int c = 0; c < 4; ++c)
#pragma unroll
    for (int p = 0; p < 4; ++p) acc[c][p] = 0.f;
  for (int ic0 = 0; ic0 < 256; ic0 += 4) {
    __syncthreads();
    for (int i = t; i < 2304; i += 256) {
      int img = i / 144, r = i % 144;
      int ic = r / 36, pix = r % 36;
      Il[((img*4 + ic)*6 + pix/6)*8 + pix%6] = in[((b0 + img)*256 + ic0 + ic)*36 + pix];
    }
    for (int i = t; i < 6400; i += 256) {
      int oc = i / 100, r = i % 100;
      int ic = r / 25, tap = r % 25;
      Wl[(ic*25 + tap)*68 + oc] = w[((oc0 + oc)*256 + ic0 + ic)*25 + tap];
    }
    __syncthreads();
#pragma unroll
    for (int ic = 0; ic < 4; ++ic) {
      const float* Ib = &Il[(ig*4 + ic)*48];
#pragma unroll
      for (int ky = 0; ky < 5; ++ky) {
        float4 a0 = *(const float4*)&Ib[ky*8];
        float4 a1 = *(const float4*)&Ib[ky*8 + 4];
        float4 c0 = *(const float4*)&Ib[(ky+1)*8];
        float4 c1 = *(const float4*)&Ib[(ky+1)*8 + 4];
        float ra[8] = {a0.x,a0.y,a0.z,a0.w,a1.x,a1.y,a1.z,a1.w};
        float rb[8] = {c0.x,c0.y,c0.z,c0.w,c1.x,c1.y,c1.z,c1.w};
#pragma unroll
        for (int kx = 0; kx < 5; ++kx) {
          float4 wv = *(const float4*)&Wl[(ic*25 + ky*5 + kx)*68 + og*4];
          float wc[4] = {wv.x, wv.y, wv.z, wv.w};
#pragma unroll
          for (int c = 0; c < 4; ++c) {
            acc[c][0] = fmaf(wc[c], ra[kx],   acc[c][0]);
            acc[c][1] = fmaf(wc[c], ra[kx+1], acc[c][1]);
            acc[c][2] = fmaf(wc[c], rb[kx],   acc[c][2]);
            acc[c][3] = fmaf(wc[c], rb[kx+1], acc[c][3]);
          }
        }
      }
    }
  }
#pragma unroll
  for (int c = 0; c < 4; ++c) {
    const int oc = oc0 + og*4 + c;
    const float bv = bias[oc];
#pragma unroll
    for (int p = 0; p < 4; ++p)
      out[((b0 + ig)*256 + oc)*4 + p] = fmaxf(acc[c][p] + bv, 0.f);
  }
}

// ============================================================================
// caps: squash -> u_hat -> 3x dynamic routing -> v_lengths + fused fc1
// (unchanged)
// ============================================================================
__global__ __launch_bounds__(256) void caps_kernel(
    const float* __restrict__ h3, const float* __restrict__ cw,
    const float* __restrict__ cb, const int* __restrict__ y,
    const float* __restrict__ fc1w, const float* __restrict__ fc1b,
    float* __restrict__ vlen, float* __restrict__ h1f)
{
  __shared__ float prim[1024];     // [64][16]
  __shared__ float uh[10240];      // [64][10][16]
  __shared__ float bij[640];
  __shared__ float cij[640];
  __shared__ float vv[160];        // [10][16]
  const int b = blockIdx.x, t = threadIdx.x;
  {
    const int cap = t >> 2, part = t & 3;
    float4 h = *(const float4*)&h3[b*1024 + cap*16 + part*4];
    float d = h.x*h.x + h.y*h.y + h.z*h.z + h.w*h.w;
    d += __shfl_xor(d, 1);
    d += __shfl_xor(d, 2);
    float sc = d / (1.f + d) / sqrtf(d + EPSF);
    float4 o4 = make_float4(h.x*sc, h.y*sc, h.z*sc, h.w*sc);
    *(float4*)&prim[cap*16 + part*4] = o4;
  }
  for (int f = t; f < 640; f += 256) bij[f] = 0.f;
  __syncthreads();
  for (int f = t; f < 10240; f += 256) {
    int i = f / 160, r = f % 160;
    int o = r >> 4, j = r & 15;
    const float* wp = cw + i*2560 + o*256 + j;   // k-stride 16
    const float* pp = prim + i*16;
    float s = 0.f;
#pragma unroll
    for (int k = 0; k < 16; ++k) s = fmaf(pp[k], wp[k*16], s);
    uh[f] = s;
  }
  __syncthreads();
  for (int r = 0; r < 3; ++r) {
    if (t < 64) {
      float e[10];
      float mx = -1e30f;
#pragma unroll
      for (int o = 0; o < 10; ++o) { e[o] = bij[t*10 + o]; mx = fmaxf(mx, e[o]); }
      float sum = 0.f;
#pragma unroll
      for (int o = 0; o < 10; ++o) { e[o] = expf(e[o] - mx); sum += e[o]; }
      float inv = 1.f / sum;
#pragma unroll
      for (int o = 0; o < 10; ++o) cij[t*10 + o] = e[o] * inv;
    }
    __syncthreads();
    if (t < 160) {
      const int o = t >> 4;
      float s = cb[t];
      for (int i = 0; i < 64; ++i) s = fmaf(cij[i*10 + o], uh[i*160 + t], s);
      float d = s*s;
      d += __shfl_xor(d, 1); d += __shfl_xor(d, 2);
      d += __shfl_xor(d, 4); d += __shfl_xor(d, 8);
      float sc = d / (1.f + d) / sqrtf(d + EPSF);
      vv[t] = s * sc;
      if (r == 2 && (t & 15) == 0)
        vlen[b*10 + o] = sqrtf(sc*sc*d + EPSF);
    }
    __syncthreads();
    if (r < 2) {
      for (int f = t; f < 640; f += 256) {
        int i = f / 10, o = f % 10;
        const float* up = &uh[i*160 + o*16];
        const float* vp = &vv[o*16];
        float a = 0.f;
#pragma unroll
        for (int j = 0; j < 16; ++j) a = fmaf(up[j], vp[j], a);
        bij[f] += a;
      }
      __syncthreads();
    }
  }
  const int yb = y[b];
  const float* vy = &vv[yb*16];
  for (int nn = t; nn < 512; nn += 256) {
    const float* wr = fc1w + nn*160 + yb*16;
    float s = fc1b[nn];
#pragma unroll
    for (int k = 0; k < 16; ++k) s = fmaf(vy[k], wr[k], s);
    h1f[b*512 + nn] = fmaxf(s, 0.f);
  }
}

// ============================================================================
// fc: out[M,N] = act(A[M,K] @ W[N,K]^T + bias) (unchanged)
// ============================================================================
template<int ACT>
__global__ __launch_bounds__(256) void fc_kernel(
    const float* __restrict__ A, const float* __restrict__ W,
    const float* __restrict__ bias, float* __restrict__ out,
    int M, int N, int K)
{
  __shared__ float Al[16*68];
  __shared__ float Bl[16*132];
  const int m0 = blockIdx.x * 64;
  const int n0 = blockIdx.y * 128;
  const int t  = threadIdx.x;
  const int tx = t & 15;
  const int ty = t >> 4;
  float acc[4][8];
#pragma unroll
  for (int i2 = 0; i2 < 4; ++i2)
#pragma unroll
    for (int j2 = 0; j2 < 8; ++j2) acc[i2][j2] = 0.f;
  for (int k0 = 0; k0 < K; k0 += 16) {
    __syncthreads();
    {
      int m = t >> 2, kq = (t & 3) * 4;
      float4 v = *(const float4*)&A[(m0 + m)*K + k0 + kq];
      Al[(kq+0)*68 + m] = v.x;
      Al[(kq+1)*68 + m] = v.y;
      Al[(kq+2)*68 + m] = v.z;
      Al[(kq+3)*68 + m] = v.w;
    }
    for (int f = t; f < 512; f += 256) {
      int nn = f >> 2, kq = (f & 3) * 4;
      float4 v = *(const float4*)&W[(n0 + nn)*K + k0 + kq];
      Bl[(kq+0)*132 + nn] = v.x;
      Bl[(kq+1)*132 + nn] = v.y;
      Bl[(kq+2)*132 + nn] = v.z;
      Bl[(kq+3)*132 + nn] = v.w;
    }
    __syncthreads();
#pragma unroll
    for (int kk = 0; kk < 16; ++kk) {
      float4 a  = *(const float4*)&Al[kk*68 + ty*4];
      float4 b0 = *(const float4*)&Bl[kk*132 + tx*8];
      float4 b1 = *(const float4*)&Bl[kk*132 + tx*8 + 4];
      float am[4] = {a.x, a.y, a.z, a.w};
      float bn[8] = {b0.x, b0.y, b0.z, b0.w, b1.x, b1.y, b1.z, b1.w};
#pragma unroll
      for (int i2 = 0; i2 < 4; ++i2)
#pragma unroll
        for (int j2 = 0; j2 < 8; ++j2)
          acc[i2][j2] = fmaf(am[i2], bn[j2], acc[i2][j2]);
    }
  }
#pragma unroll
  for (int i2 = 0; i2 < 4; ++i2) {
    const int m = m0 + ty*4 + i2;
#pragma unroll
    for (int j2 = 0; j2 < 8; ++j2) {
      const int nn = n0 + tx*8 + j2;
      float v = acc[i2][j2] + bias[nn];
      if (ACT == 0) v = fmaxf(v, 0.f);
      else          v = 1.f / (1.f + expf(-v));
      out[m*N + nn] = v;
    }
  }
}

// ============================================================================
extern "C" void kernel_launch(void* const* d_in, const int* in_sizes, int n_in,
                              void* d_out, int out_size, void* d_ws, size_t ws_size,
                              hipStream_t stream) {
  const float* x       = (const float*)d_in[0];
  const int*   y       = (const int*)  d_in[1];
  const float* conv1_w = (const float*)d_in[2];
  const float* conv1_b = (const float*)d_in[3];
  const float* conv2_w = (const float*)d_in[4];
  const float* conv2_b = (const float*)d_in[5];
  const float* conv3_w = (const float*)d_in[6];
  const float* conv3_b = (const float*)d_in[7];
  const float* caps_w  = (const float*)d_in[8];
  const float* caps_b  = (const float*)d_in[9];
  const float* fc1_w   = (const float*)d_in[10];
  const float* fc1_b   = (const float*)d_in[11];
  const float* fc2_w   = (const float*)d_in[12];
  const float* fc2_b   = (const float*)d_in[13];
  const float* fc3_w   = (const float*)d_in[14];
  const float* fc3_b   = (const float*)d_in[15];
  float* out = (float*)d_out;
  float* ws  = (float*)d_ws;

  // ws layout (float units), total 27,213,824 floats = 108.9 MB
  __hip_bfloat16* h1t = (__hip_bfloat16*)ws;            // 29,491,200 bf16
  __hip_bfloat16* wtb = (__hip_bfloat16*)(ws + 14745600); //  819,200 bf16
  float* h2c = ws + 15155200;      // 9,437,184
  float* h3c = ws + 24592384;      // 1,048,576
  float* h1f = ws + 25640960;      //   524,288
  float* h2f = ws + 26165248;      // 1,048,576

  wtrans_kernel<<<dim3(3200),     256, 0, stream>>>(conv2_w, wtb);
  conv1_kernel<<<dim3(1024, 4),   256, 0, stream>>>(x, conv1_w, conv1_b, h1t);
  conv2_mfma_kernel<<<dim3(512),  256, 0, stream>>>(h1t, wtb, conv2_b, h2c);
  conv3_kernel<<<dim3(64, 4),     256, 0, stream>>>(h2c, conv3_w, conv3_b, h3c);
  caps_kernel<<<dim3(1024),       256, 0, stream>>>(h3c, caps_w, caps_b, y,
                                                    fc1_w, fc1_b, out, h1f);
  fc_kernel<0><<<dim3(16, 8),  256, 0, stream>>>(h1f, fc2_w, fc2_b, h2f,
                                                 1024, 1024, 512);
  fc_kernel<1><<<dim3(16, 24), 256, 0, stream>>>(h2f, fc3_w, fc3_b, out + 10240,
                                                 1024, 3072, 1024);
}

// Round 3
// 618.136 us; speedup vs baseline: 4.7585x; 1.7980x over previous
//
#include <hip/hip_runtime.h>
#include <hip/hip_bf16.h>
#include <math.h>

#define EPSF 1e-7f

typedef __attribute__((ext_vector_type(8))) short bhalf8;   // 8 bf16 (4 VGPRs)
typedef __attribute__((ext_vector_type(4))) float floatx4;  // MFMA acc

__device__ __forceinline__ void gload_lds16(const void* g, void* l) {
  __builtin_amdgcn_global_load_lds(
      (const __attribute__((address_space(1))) unsigned int*)g,
      (__attribute__((address_space(3))) unsigned int*)l,
      16, 0, 0);
}

// ============================================================================
// conv1: x[1024,3,32,32] -> h1t[1024,225,128] bf16 (position-major, ic inner)
// 3x3 stride2, ReLU. block = (image, 32-oc tile); thread = one output position
// ============================================================================
__global__ __launch_bounds__(256) void conv1_kernel(
    const float* __restrict__ x, const float* __restrict__ w,
    const float* __restrict__ bias, __hip_bfloat16* __restrict__ out)
{
  const int b   = blockIdx.x;
  const int oc0 = blockIdx.y * 32;
  const int t   = threadIdx.x;
  if (t >= 225) return;
  const int py = t / 15, px = t % 15;
  const float* xb = x + b * 3072;
  float win[27];
#pragma unroll
  for (int c = 0; c < 3; ++c)
#pragma unroll
    for (int ky = 0; ky < 3; ++ky)
#pragma unroll
      for (int kx = 0; kx < 3; ++kx)
        win[c*9 + ky*3 + kx] = xb[c*1024 + (py*2 + ky)*32 + (px*2 + kx)];
  __hip_bfloat16 hv[32];
  for (int oc = 0; oc < 32; ++oc) {
    const float* wp = w + (oc0 + oc) * 27;   // oc uniform -> scalar loads
    float acc = bias[oc0 + oc];
#pragma unroll
    for (int q = 0; q < 27; ++q) acc = fmaf(win[q], wp[q], acc);
    hv[oc] = __float2bfloat16(fmaxf(acc, 0.f));
  }
  uint4* dst = (uint4*)&out[((size_t)b*225 + t)*128 + oc0];
  const uint4* src = (const uint4*)hv;
#pragma unroll
  for (int q = 0; q < 4; ++q) dst[q] = src[q];
}

// ============================================================================
// wtrans2: conv2_w fp32 [oc][ic][5][5] -> Wt bf16 [oc][k], k = tap*128 + ic
// ============================================================================
__global__ __launch_bounds__(256) void wtrans_kernel(
    const float* __restrict__ w, __hip_bfloat16* __restrict__ wt)
{
  int i = blockIdx.x*256 + threadIdx.x;          // 819,200 total
  int oc = i / 3200, r = i - oc*3200;
  int tap = r >> 7, ic = r & 127;
  wt[i] = __float2bfloat16(w[(oc*128 + ic)*25 + tap]);
}

// ============================================================================
// wtrans3: conv3_w fp32 [oc][ic][5][5] -> Wt bf16 [oc][k], k = tap*256 + ic
// ============================================================================
__global__ __launch_bounds__(256) void wtrans3_kernel(
    const float* __restrict__ w, __hip_bfloat16* __restrict__ wt)
{
  int i = blockIdx.x*256 + threadIdx.x;          // 1,638,400 total
  int oc = i / 6400, r = i - oc*6400;
  int tap = r >> 8, ic = r & 255;
  wt[i] = __float2bfloat16(w[(oc*256 + ic)*25 + tap]);
}

// ============================================================================
// conv2_mfma: h1t[1024,225,128]bf16 -> h2t[1024,36,256]bf16, 5x5 s2, ReLU
// GEMM view: M=(img,pos) 72/block, N=oc 256, K=tap*128+ic 3200.
// epilogue now emits bf16 position-major so conv3_mfma can consume directly.
// ============================================================================
__global__ __launch_bounds__(256) void conv2_mfma_kernel(
    const __hip_bfloat16* __restrict__ a,   // h1t
    const __hip_bfloat16* __restrict__ wt,  // Wt [256][3200]
    const float* __restrict__ bias,
    __hip_bfloat16* __restrict__ out)       // h2t [1024][36][256]
{
  __shared__ __align__(16) unsigned short Il[2*225*136];  // 122,400 B
  __shared__ uint4 Bl[2048];                              //  32,768 B
  const int b0   = blockIdx.x * 2;
  const int t    = threadIdx.x;
  const int lane = t & 63;
  const int w    = t >> 6;
  const int n    = lane & 15;
  const int g    = lane >> 4;

  // ---- stage both input images: global [pix][128ic] -> LDS [pix][136] ----
  for (int i = t; i < 7200; i += 256) {
    int img = (i >= 3600);
    int r = i - img*3600;
    int p = r >> 4, c = r & 15;
    uint4 v = *(const uint4*)((const char*)a +
              (((size_t)(b0+img)*225 + p)*256 + c*16));
    *(uint4*)((char*)Il + ((img*225 + p)*136 + c*8)*2) = v;
  }

  // ---- B staging: per-lane const global offset; 4 x 1KB issues per wave ----
  const int oc_l = lane >> 2;                        // oc within 16-row group
  const int kq_l = (lane & 3) ^ ((lane >> 3) & 3);   // swizzle inverse
  const char* gB = (const char*)wt +
                   (size_t)(w*64 + oc_l)*6400 + kq_l*16;
  char* BlBase = (char*)Bl;
#pragma unroll
  for (int jj = 0; jj < 4; ++jj)                     // step 0 -> buf 0
    gload_lds16(gB + (size_t)jj*16*6400, BlBase + (w*4 + jj)*1024);
  gB += 64;

  // ---- per-lane fragment base addresses ----
  int Abase[5];
#pragma unroll
  for (int mt = 0; mt < 5; ++mt) {
    int m  = mt*16 + n;
    int mm = (m < 72) ? m : 0;          // pad lanes read img0/pos0 (unused)
    int img = (mm >= 36);
    int pos = mm - img*36;
    int py = pos / 6, px = pos - py*6;
    Abase[mt] = ((img*225 + (2*py)*15 + 2*px)*136 + g*8) * 2;   // bytes
  }
  int Bbase[4];
#pragma unroll
  for (int nt = 0; nt < 4; ++nt) {
    int oc = w*64 + nt*16 + n;
    Bbase[nt] = (oc*4 + (g ^ ((n >> 1) & 3))) * 16;             // bytes
  }

  floatx4 acc[5][4];
#pragma unroll
  for (int mt = 0; mt < 5; ++mt)
#pragma unroll
    for (int nt = 0; nt < 4; ++nt)
      acc[mt][nt] = (floatx4){0.f, 0.f, 0.f, 0.f};

  __syncthreads();   // Il staged + buf0 loaded (vmcnt/lgkmcnt drained)

  int s = 0;
#pragma unroll 1
  for (int ky = 0; ky < 5; ++ky) {
#pragma unroll 1
    for (int kx = 0; kx < 5; ++kx) {
      const int tapoff = (ky*15 + kx) * 272;   // pixel offset in bytes
#pragma unroll
      for (int icq = 0; icq < 4; ++icq, ++s) {
        const int par = s & 1;
        if (s < 99) {                          // prefetch step s+1 -> buf^1
          char* dstb = BlBase + ((s+1)&1)*16384 + w*4096;
#pragma unroll
          for (int jj = 0; jj < 4; ++jj)
            gload_lds16(gB + (size_t)jj*16*6400, dstb + jj*1024);
          gB += 64;
        }
        bhalf8 bf[4];
        const char* bp = BlBase + par*16384;
#pragma unroll
        for (int nt = 0; nt < 4; ++nt)
          bf[nt] = *(const bhalf8*)(bp + Bbase[nt]);
#pragma unroll
        for (int mt = 0; mt < 5; ++mt) {
          bhalf8 af = *(const bhalf8*)((const char*)Il +
                       Abase[mt] + tapoff + icq*64);
#pragma unroll
          for (int nt = 0; nt < 4; ++nt)
            acc[mt][nt] = __builtin_amdgcn_mfma_f32_16x16x32_bf16(
                af, bf[nt], acc[mt][nt], 0, 0, 0);
        }
        __syncthreads();
      }
    }
  }

  // ---- epilogue: D row=g*4+r (m), col=n (oc). write bf16 [img][pos][oc] ----
  float bv[4];
#pragma unroll
  for (int nt = 0; nt < 4; ++nt) bv[nt] = bias[w*64 + nt*16 + n];
#pragma unroll
  for (int mt = 0; mt < 5; ++mt) {
#pragma unroll
    for (int r = 0; r < 4; ++r) {
      int m = mt*16 + g*4 + r;
      if (m < 72) {
        int img = (m >= 36);
        int pos = m - img*36;
        __hip_bfloat16* op = out + (((size_t)(b0+img)*36 + pos)*256 + w*64 + n);
#pragma unroll
        for (int nt = 0; nt < 4; ++nt)
          op[nt*16] = __float2bfloat16(fmaxf(acc[mt][nt][r] + bv[nt], 0.f));
      }
    }
  }
}

// ============================================================================
// conv3_mfma: h2t[1024,36,256]bf16 -> h3[1024,256,2,2]fp32, 5x5 s1, ReLU
// GEMM view: M=(img,pos) 16/block (4 images), N=oc 256, K=tap*256+ic 6400.
// LDS: Il[4img][36pix][272pad]+8/img pad (A reads 2-way=free),
//      Bl 2x32KB double-buffered 64-k weight slices, XOR chunk swizzle.
// grid=256 -> 1 block/CU; floor = B L2 traffic 819MB ~ 24us.
// ============================================================================
__global__ __launch_bounds__(256) void conv3_mfma_kernel(
    const __hip_bfloat16* __restrict__ a,   // h2t [1024][36][256]
    const __hip_bfloat16* __restrict__ wt,  // Wt3 [256][6400]
    const float* __restrict__ bias,
    float* __restrict__ out)                // h3 [1024][256][4]
{
  __shared__ __align__(16) unsigned short Il[4*10072];    // 80,576 B (img stride 10072 elems)
  __shared__ uint4 Bl[4096];                              // 65,536 B
  const int b0   = blockIdx.x * 4;
  const int t    = threadIdx.x;
  const int lane = t & 63;
  const int w    = t >> 6;
  const int n    = lane & 15;
  const int g    = lane >> 4;

  // ---- stage 4 input images: global [pix][256ic] -> LDS [pix][272pad] ----
  for (int i = t; i < 4608; i += 256) {
    int img = i / 1152, r = i - img*1152;    // 36 pix * 32 chunks
    int p = r >> 5, c = r & 31;
    uint4 v = *(const uint4*)((const char*)a +
              ((((size_t)(b0+img)*36 + p) << 9) + c*16));
    *(uint4*)((char*)Il + img*20144 + p*544 + c*16) = v;
  }

  // ---- B staging: 8 x 1KB per wave per step (64 oc x 64 k = 8KB) ----
  const int ocl = lane >> 3;                 // 0..7
  const int kql = (lane & 7) ^ ocl;          // swizzle inverse
  const char* gB = (const char*)wt + (size_t)(w*64 + ocl)*12800 + kql*16;
  char* BlBase = (char*)Bl;
#pragma unroll
  for (int jj = 0; jj < 8; ++jj)             // step 0 -> buf 0
    gload_lds16(gB + (size_t)jj*8*12800, BlBase + (w*8 + jj)*1024);
  gB += 128;

  // ---- per-lane fragment bases ----
  int Abase;
  {
    int img = n >> 2, pos = n & 3;
    int py = pos >> 1, px = pos & 1;
    Abase = img*20144 + (py*6 + px)*544 + g*16;       // bytes
  }
  int Bbase[4][2];
#pragma unroll
  for (int nt = 0; nt < 4; ++nt) {
    int oc = w*64 + nt*16 + n;
#pragma unroll
    for (int h = 0; h < 2; ++h)
      Bbase[nt][h] = (oc*8 + ((h*4 + g) ^ (n & 7))) * 16;   // bytes
  }

  floatx4 acc[4];
#pragma unroll
  for (int nt = 0; nt < 4; ++nt) acc[nt] = (floatx4){0.f, 0.f, 0.f, 0.f};

  __syncthreads();

  int s = 0;
#pragma unroll 1
  for (int ky = 0; ky < 5; ++ky) {
#pragma unroll 1
    for (int kx = 0; kx < 5; ++kx) {
      const int tapoff = (ky*6 + kx) * 544;  // pixel offset bytes
#pragma unroll
      for (int ip = 0; ip < 4; ++ip, ++s) {  // 64-k pairs within tap
        const int par = s & 1;
        if (s < 99) {                        // prefetch step s+1 -> buf^1
          char* dstb = BlBase + ((s+1)&1)*32768 + w*8192;
#pragma unroll
          for (int jj = 0; jj < 8; ++jj)
            gload_lds16(gB + (size_t)jj*8*12800, dstb + jj*1024);
          gB += 128;
        }
        const char* bp = BlBase + par*32768;
        bhalf8 bf[4][2];
#pragma unroll
        for (int nt = 0; nt < 4; ++nt) {
          bf[nt][0] = *(const bhalf8*)(bp + Bbase[nt][0]);
          bf[nt][1] = *(const bhalf8*)(bp + Bbase[nt][1]);
        }
        const char* ap = (const char*)Il + Abase + tapoff + ip*128;
        bhalf8 a0 = *(const bhalf8*)(ap);
        bhalf8 a1 = *(const bhalf8*)(ap + 64);
#pragma unroll
        for (int nt = 0; nt < 4; ++nt) {
          acc[nt] = __builtin_amdgcn_mfma_f32_16x16x32_bf16(
              a0, bf[nt][0], acc[nt], 0, 0, 0);
          acc[nt] = __builtin_amdgcn_mfma_f32_16x16x32_bf16(
              a1, bf[nt][1], acc[nt], 0, 0, 0);
        }
        __syncthreads();
      }
    }
  }

  // ---- epilogue: row = g*4+r = (img,pos), col = n -> oc; fp32 [b][oc][4] ----
  float bv[4];
#pragma unroll
  for (int nt = 0; nt < 4; ++nt) bv[nt] = bias[w*64 + nt*16 + n];
#pragma unroll
  for (int r = 0; r < 4; ++r) {
    int m = g*4 + r;
    int img = m >> 2, pos = m & 3;
    float* op = out + (((size_t)(b0+img)*256 + w*64 + n)*4 + pos);
#pragma unroll
    for (int nt = 0; nt < 4; ++nt)
      op[nt*64] = fmaxf(acc[nt][r] + bv[nt], 0.f);
  }
}

// ============================================================================
// caps: squash -> u_hat -> 3x dynamic routing -> v_lengths + fused fc1
// ============================================================================
__global__ __launch_bounds__(256) void caps_kernel(
    const float* __restrict__ h3, const float* __restrict__ cw,
    const float* __restrict__ cb, const int* __restrict__ y,
    const float* __restrict__ fc1w, const float* __restrict__ fc1b,
    float* __restrict__ vlen, float* __restrict__ h1f)
{
  __shared__ float prim[1024];     // [64][16]
  __shared__ float uh[10240];      // [64][10][16]
  __shared__ float bij[640];
  __shared__ float cij[640];
  __shared__ float vv[160];        // [10][16]
  const int b = blockIdx.x, t = threadIdx.x;
  {
    const int cap = t >> 2, part = t & 3;
    float4 h = *(const float4*)&h3[b*1024 + cap*16 + part*4];
    float d = h.x*h.x + h.y*h.y + h.z*h.z + h.w*h.w;
    d += __shfl_xor(d, 1);
    d += __shfl_xor(d, 2);
    float sc = d / (1.f + d) / sqrtf(d + EPSF);
    float4 o4 = make_float4(h.x*sc, h.y*sc, h.z*sc, h.w*sc);
    *(float4*)&prim[cap*16 + part*4] = o4;
  }
  for (int f = t; f < 640; f += 256) bij[f] = 0.f;
  __syncthreads();
  for (int f = t; f < 10240; f += 256) {
    int i = f / 160, r = f % 160;
    int o = r >> 4, j = r & 15;
    const float* wp = cw + i*2560 + o*256 + j;   // k-stride 16
    const float* pp = prim + i*16;
    float s = 0.f;
#pragma unroll
    for (int k = 0; k < 16; ++k) s = fmaf(pp[k], wp[k*16], s);
    uh[f] = s;
  }
  __syncthreads();
  for (int r = 0; r < 3; ++r) {
    if (t < 64) {
      float e[10];
      float mx = -1e30f;
#pragma unroll
      for (int o = 0; o < 10; ++o) { e[o] = bij[t*10 + o]; mx = fmaxf(mx, e[o]); }
      float sum = 0.f;
#pragma unroll
      for (int o = 0; o < 10; ++o) { e[o] = expf(e[o] - mx); sum += e[o]; }
      float inv = 1.f / sum;
#pragma unroll
      for (int o = 0; o < 10; ++o) cij[t*10 + o] = e[o] * inv;
    }
    __syncthreads();
    if (t < 160) {
      const int o = t >> 4;
      float s = cb[t];
      for (int i = 0; i < 64; ++i) s = fmaf(cij[i*10 + o], uh[i*160 + t], s);
      float d = s*s;
      d += __shfl_xor(d, 1); d += __shfl_xor(d, 2);
      d += __shfl_xor(d, 4); d += __shfl_xor(d, 8);
      float sc = d / (1.f + d) / sqrtf(d + EPSF);
      vv[t] = s * sc;
      if (r == 2 && (t & 15) == 0)
        vlen[b*10 + o] = sqrtf(sc*sc*d + EPSF);
    }
    __syncthreads();
    if (r < 2) {
      for (int f = t; f < 640; f += 256) {
        int i = f / 10, o = f % 10;
        const float* up = &uh[i*160 + o*16];
        const float* vp = &vv[o*16];
        float a = 0.f;
#pragma unroll
        for (int j = 0; j < 16; ++j) a = fmaf(up[j], vp[j], a);
        bij[f] += a;
      }
      __syncthreads();
    }
  }
  const int yb = y[b];
  const float* vy = &vv[yb*16];
  for (int nn = t; nn < 512; nn += 256) {
    const float* wr = fc1w + nn*160 + yb*16;
    float s = fc1b[nn];
#pragma unroll
    for (int k = 0; k < 16; ++k) s = fmaf(vy[k], wr[k], s);
    h1f[b*512 + nn] = fmaxf(s, 0.f);
  }
}

// ============================================================================
// fc: out[M,N] = act(A[M,K] @ W[N,K]^T + bias). ACT: 0 = relu, 1 = sigmoid
// ============================================================================
template<int ACT>
__global__ __launch_bounds__(256) void fc_kernel(
    const float* __restrict__ A, const float* __restrict__ W,
    const float* __restrict__ bias, float* __restrict__ out,
    int M, int N, int K)
{
  __shared__ float Al[16*68];
  __shared__ float Bl[16*132];
  const int m0 = blockIdx.x * 64;
  const int n0 = blockIdx.y * 128;
  const int t  = threadIdx.x;
  const int tx = t & 15;
  const int ty = t >> 4;
  float acc[4][8];
#pragma unroll
  for (int i2 = 0; i2 < 4; ++i2)
#pragma unroll
    for (int j2 = 0; j2 < 8; ++j2) acc[i2][j2] = 0.f;
  for (int k0 = 0; k0 < K; k0 += 16) {
    __syncthreads();
    {
      int m = t >> 2, kq = (t & 3) * 4;
      float4 v = *(const float4*)&A[(m0 + m)*K + k0 + kq];
      Al[(kq+0)*68 + m] = v.x;
      Al[(kq+1)*68 + m] = v.y;
      Al[(kq+2)*68 + m] = v.z;
      Al[(kq+3)*68 + m] = v.w;
    }
    for (int f = t; f < 512; f += 256) {
      int nn = f >> 2, kq = (f & 3) * 4;
      float4 v = *(const float4*)&W[(n0 + nn)*K + k0 + kq];
      Bl[(kq+0)*132 + nn] = v.x;
      Bl[(kq+1)*132 + nn] = v.y;
      Bl[(kq+2)*132 + nn] = v.z;
      Bl[(kq+3)*132 + nn] = v.w;
    }
    __syncthreads();
#pragma unroll
    for (int kk = 0; kk < 16; ++kk) {
      float4 a  = *(const float4*)&Al[kk*68 + ty*4];
      float4 b0 = *(const float4*)&Bl[kk*132 + tx*8];
      float4 b1 = *(const float4*)&Bl[kk*132 + tx*8 + 4];
      float am[4] = {a.x, a.y, a.z, a.w};
      float bn[8] = {b0.x, b0.y, b0.z, b0.w, b1.x, b1.y, b1.z, b1.w};
#pragma unroll
      for (int i2 = 0; i2 < 4; ++i2)
#pragma unroll
        for (int j2 = 0; j2 < 8; ++j2)
          acc[i2][j2] = fmaf(am[i2], bn[j2], acc[i2][j2]);
    }
  }
#pragma unroll
  for (int i2 = 0; i2 < 4; ++i2) {
    const int m = m0 + ty*4 + i2;
#pragma unroll
    for (int j2 = 0; j2 < 8; ++j2) {
      const int nn = n0 + tx*8 + j2;
      float v = acc[i2][j2] + bias[nn];
      if (ACT == 0) v = fmaxf(v, 0.f);
      else          v = 1.f / (1.f + expf(-v));
      out[m*N + nn] = v;
    }
  }
}

// ============================================================================
extern "C" void kernel_launch(void* const* d_in, const int* in_sizes, int n_in,
                              void* d_out, int out_size, void* d_ws, size_t ws_size,
                              hipStream_t stream) {
  const float* x       = (const float*)d_in[0];
  const int*   y       = (const int*)  d_in[1];
  const float* conv1_w = (const float*)d_in[2];
  const float* conv1_b = (const float*)d_in[3];
  const float* conv2_w = (const float*)d_in[4];
  const float* conv2_b = (const float*)d_in[5];
  const float* conv3_w = (const float*)d_in[6];
  const float* conv3_b = (const float*)d_in[7];
  const float* caps_w  = (const float*)d_in[8];
  const float* caps_b  = (const float*)d_in[9];
  const float* fc1_w   = (const float*)d_in[10];
  const float* fc1_b   = (const float*)d_in[11];
  const float* fc2_w   = (const float*)d_in[12];
  const float* fc2_b   = (const float*)d_in[13];
  const float* fc3_w   = (const float*)d_in[14];
  const float* fc3_b   = (const float*)d_in[15];
  float* out = (float*)d_out;
  float* ws  = (float*)d_ws;

  // ws layout (float units), total 23,314,432 floats = 93.3 MB
  __hip_bfloat16* h1t = (__hip_bfloat16*)ws;                 // 29,491,200 bf16
  __hip_bfloat16* wt2 = (__hip_bfloat16*)(ws + 14745600);    //    819,200 bf16
  __hip_bfloat16* wt3 = (__hip_bfloat16*)(ws + 15155200);    //  1,638,400 bf16
  __hip_bfloat16* h2t = (__hip_bfloat16*)(ws + 15974400);    //  9,437,184 bf16
  float* h3c = ws + 20692992;      // 1,048,576
  float* h1f = ws + 21741568;      //   524,288
  float* h2f = ws + 22265856;      // 1,048,576

  wtrans_kernel <<<dim3(3200),    256, 0, stream>>>(conv2_w, wt2);
  wtrans3_kernel<<<dim3(6400),    256, 0, stream>>>(conv3_w, wt3);
  conv1_kernel<<<dim3(1024, 4),   256, 0, stream>>>(x, conv1_w, conv1_b, h1t);
  conv2_mfma_kernel<<<dim3(512),  256, 0, stream>>>(h1t, wt2, conv2_b, h2t);
  conv3_mfma_kernel<<<dim3(256),  256, 0, stream>>>(h2t, wt3, conv3_b, h3c);
  caps_kernel<<<dim3(1024),       256, 0, stream>>>(h3c, caps_w, caps_b, y,
                                                    fc1_w, fc1_b, out, h1f);
  fc_kernel<0><<<dim3(16, 8),  256, 0, stream>>>(h1f, fc2_w, fc2_b, h2f,
                                                 1024, 1024, 512);
  fc_kernel<1><<<dim3(16, 24), 256, 0, stream>>>(h2f, fc3_w, fc3_b, out + 10240,
                                                 1024, 3072, 1024);
}

// Round 4
// 608.412 us; speedup vs baseline: 4.8346x; 1.0160x over previous
//
#include <hip/hip_runtime.h>
#include <hip/hip_bf16.h>
#include <math.h>

#define EPSF 1e-7f

typedef __attribute__((ext_vector_type(8))) short bhalf8;   // 8 bf16 (4 VGPRs)
typedef __attribute__((ext_vector_type(4))) float floatx4;  // MFMA acc

// ============================================================================
// conv1: x[1024,3,32,32] -> h1t[1024,225,128] bf16 (position-major, ic inner)
// 3x3 stride2, ReLU. block = (image, 32-oc tile); thread = one output position
// ============================================================================
__global__ __launch_bounds__(256) void conv1_kernel(
    const float* __restrict__ x, const float* __restrict__ w,
    const float* __restrict__ bias, __hip_bfloat16* __restrict__ out)
{
  const int b   = blockIdx.x;
  const int oc0 = blockIdx.y * 32;
  const int t   = threadIdx.x;
  if (t >= 225) return;
  const int py = t / 15, px = t % 15;
  const float* xb = x + b * 3072;
  float win[27];
#pragma unroll
  for (int c = 0; c < 3; ++c)
#pragma unroll
    for (int ky = 0; ky < 3; ++ky)
#pragma unroll
      for (int kx = 0; kx < 3; ++kx)
        win[c*9 + ky*3 + kx] = xb[c*1024 + (py*2 + ky)*32 + (px*2 + kx)];
  __hip_bfloat16 hv[32];
  for (int oc = 0; oc < 32; ++oc) {
    const float* wp = w + (oc0 + oc) * 27;   // oc uniform -> scalar loads
    float acc = bias[oc0 + oc];
#pragma unroll
    for (int q = 0; q < 27; ++q) acc = fmaf(win[q], wp[q], acc);
    hv[oc] = __float2bfloat16(fmaxf(acc, 0.f));
  }
  uint4* dst = (uint4*)&out[((size_t)b*225 + t)*128 + oc0];
  const uint4* src = (const uint4*)hv;
#pragma unroll
  for (int q = 0; q < 4; ++q) dst[q] = src[q];
}

// ============================================================================
// wtrans2: conv2_w fp32 [oc][ic][5][5] -> Wt bf16 [oc][k], k = tap*128 + ic
// ============================================================================
__global__ __launch_bounds__(256) void wtrans_kernel(
    const float* __restrict__ w, __hip_bfloat16* __restrict__ wt)
{
  int i = blockIdx.x*256 + threadIdx.x;          // 819,200 total
  int oc = i / 3200, r = i - oc*3200;
  int tap = r >> 7, ic = r & 127;
  wt[i] = __float2bfloat16(w[(oc*128 + ic)*25 + tap]);
}

// ============================================================================
// wtrans3: conv3_w fp32 [oc][ic][5][5] -> Wt bf16 [oc][k], k = tap*256 + ic
// ============================================================================
__global__ __launch_bounds__(256) void wtrans3_kernel(
    const float* __restrict__ w, __hip_bfloat16* __restrict__ wt)
{
  int i = blockIdx.x*256 + threadIdx.x;          // 1,638,400 total
  int oc = i / 6400, r = i - oc*6400;
  int tap = r >> 8, ic = r & 255;
  wt[i] = __float2bfloat16(w[(oc*256 + ic)*25 + tap]);
}

// ============================================================================
// conv2_mfma: h1t[1024,225,128]bf16 -> h2t[1024,36,256]bf16, 5x5 s2, ReLU
// GEMM view: M=72 (2 img), N=256, K=3200. NO barrier in K-loop:
//  - A input-stationary in LDS (read-only after one sync), chunk-swizzled
//    (col = (chunk + (pix>>1)) & 15) to break the 4-way even-pixel conflict.
//  - B global->VGPR, distance-2 register double-buffer (L2-resident wt2).
// ============================================================================
__global__ __launch_bounds__(256) void conv2_mfma_kernel(
    const __hip_bfloat16* __restrict__ a,   // h1t [1024][225][128]
    const __hip_bfloat16* __restrict__ wt,  // Wt2 [256][3200]
    const float* __restrict__ bias,
    __hip_bfloat16* __restrict__ out)       // h2t [1024][36][256]
{
  __shared__ __align__(16) unsigned short Il[2*225*136];  // 122,400 B
  const int b0   = blockIdx.x * 2;
  const int t    = threadIdx.x;
  const int lane = t & 63;
  const int w    = t >> 6;
  const int n    = lane & 15;
  const int g    = lane >> 4;

  // B fragment base: oc row = w*64 + nt*16 + n, k col = s*32 + g*8
  // frag(nt,s) at gB + nt*102400 + s*64 bytes   (row = 6400 B)
  const char* gB = (const char*)(wt + (size_t)(w*64 + n)*3200 + g*8);

  bhalf8 bb[2][4];                      // [slot][nt], slot = s&1
#pragma unroll
  for (int nt = 0; nt < 4; ++nt) bb[0][nt] = *(const bhalf8*)(gB + nt*102400);
#pragma unroll
  for (int nt = 0; nt < 4; ++nt) bb[1][nt] = *(const bhalf8*)(gB + nt*102400 + 64);

  // ---- stage 2 images: [pix][128ic] -> LDS [pix][136], chunk-swizzled ----
  for (int i = t; i < 7200; i += 256) {
    int img = (i >= 3600);
    int r = i - img*3600;
    int p = r >> 4, c = r & 15;
    uint4 v = *(const uint4*)((const char*)a +
              (((size_t)(b0+img)*225 + p)*256 + c*16));
    int csw = (c + (p >> 1)) & 15;
    *(uint4*)((char*)Il + ((img*225 + p)*136 + csw*8)*2) = v;
  }

  // ---- per-lane M geometry ----
  int rowb[5], pixb[5];
#pragma unroll
  for (int mt = 0; mt < 5; ++mt) {
    int m  = mt*16 + n;
    int mm = (m < 72) ? m : 0;          // pad lanes read img0/pos0 (unused)
    int img = (mm >= 36);
    int pos = mm - img*36;
    int py = pos/6, px = pos - py*6;
    pixb[mt] = 30*py + 2*px;            // base pixel (always even)
    rowb[mt] = img*225*136;             // element offset of image plane
  }

  floatx4 acc[5][4];
#pragma unroll
  for (int mt = 0; mt < 5; ++mt)
#pragma unroll
    for (int nt = 0; nt < 4; ++nt)
      acc[mt][nt] = (floatx4){0.f, 0.f, 0.f, 0.f};

  __syncthreads();   // Il staged; the ONLY barrier

  int s = 0;
#pragma unroll 1
  for (int ky = 0; ky < 5; ++ky) {
#pragma unroll 1
    for (int kx = 0; kx < 5; ++kx) {
      const int dpix = ky*15 + kx;
      int prow[5], pq[5];
#pragma unroll
      for (int mt = 0; mt < 5; ++mt) {
        int p = pixb[mt] + dpix;
        prow[mt] = rowb[mt] + p*136;
        pq[mt]   = p >> 1;
      }
#pragma unroll
      for (int icq = 0; icq < 4; ++icq) {
        const int scur = s + icq;
        // A fragments (swizzled column)
        bhalf8 af[5];
#pragma unroll
        for (int mt = 0; mt < 5; ++mt) {
          int csw = ((icq*4 + g) + pq[mt]) & 15;
          af[mt] = *(const bhalf8*)((const char*)Il + (prow[mt] + csw*8)*2);
        }
        // MFMAs consume slot (icq&1)
#pragma unroll
        for (int mt = 0; mt < 5; ++mt)
#pragma unroll
          for (int nt = 0; nt < 4; ++nt)
            acc[mt][nt] = __builtin_amdgcn_mfma_f32_16x16x32_bf16(
                af[mt], bb[icq & 1][nt], acc[mt][nt], 0, 0, 0);
        // prefetch step scur+2 into the slot just consumed
        {
          const int spre = (scur + 2 <= 99) ? (scur + 2) : 98;
          const char* pB = gB + spre*64;
#pragma unroll
          for (int nt = 0; nt < 4; ++nt)
            bb[icq & 1][nt] = *(const bhalf8*)(pB + nt*102400);
        }
      }
      s += 4;
    }
  }

  // ---- epilogue: D row=g*4+r (m), col=n (oc). write bf16 [img][pos][oc] ----
  float bv[4];
#pragma unroll
  for (int nt = 0; nt < 4; ++nt) bv[nt] = bias[w*64 + nt*16 + n];
#pragma unroll
  for (int mt = 0; mt < 5; ++mt) {
#pragma unroll
    for (int r = 0; r < 4; ++r) {
      int m = mt*16 + g*4 + r;
      if (m < 72) {
        int img = (m >= 36);
        int pos = m - img*36;
        __hip_bfloat16* op = out + (((size_t)(b0+img)*36 + pos)*256 + w*64 + n);
#pragma unroll
        for (int nt = 0; nt < 4; ++nt)
          op[nt*16] = __float2bfloat16(fmaxf(acc[mt][nt][r] + bv[nt], 0.f));
      }
    }
  }
}

// ============================================================================
// conv3_mfma: h2t[1024,36,256]bf16 -> h3[1024,256,2,2]fp32, 5x5 s1, ReLU
// Same no-barrier structure: A (4 images) in LDS (2-way reads = free),
// B global->VGPR distance-2 double-buffer. M=16, N=256, K=6400.
// ============================================================================
__global__ __launch_bounds__(256) void conv3_mfma_kernel(
    const __hip_bfloat16* __restrict__ a,   // h2t [1024][36][256]
    const __hip_bfloat16* __restrict__ wt,  // Wt3 [256][6400]
    const float* __restrict__ bias,
    float* __restrict__ out)                // h3 [1024][256][4]
{
  __shared__ __align__(16) unsigned short Il[4*10072];    // 80,576 B
  const int b0   = blockIdx.x * 4;
  const int t    = threadIdx.x;
  const int lane = t & 63;
  const int w    = t >> 6;
  const int n    = lane & 15;
  const int g    = lane >> 4;

  // B fragment base: oc row = w*64 + nt*16 + n (row = 12800 B)
  // frag(nt,h,s) at gB + nt*204800 + s*128 + h*64 bytes
  const char* gB = (const char*)(wt + (size_t)(w*64 + n)*6400 + g*8);

  bhalf8 bb[2][4][2];                   // [slot][nt][h], slot = s&1
#pragma unroll
  for (int nt = 0; nt < 4; ++nt) {
    bb[0][nt][0] = *(const bhalf8*)(gB + nt*204800);
    bb[0][nt][1] = *(const bhalf8*)(gB + nt*204800 + 64);
    bb[1][nt][0] = *(const bhalf8*)(gB + nt*204800 + 128);
    bb[1][nt][1] = *(const bhalf8*)(gB + nt*204800 + 192);
  }

  // ---- stage 4 input images: [pix][256ic] -> LDS [pix][272pad] ----
  for (int i = t; i < 4608; i += 256) {
    int img = i / 1152, r = i - img*1152;    // 36 pix * 32 chunks
    int p = r >> 5, c = r & 31;
    uint4 v = *(const uint4*)((const char*)a +
              ((((size_t)(b0+img)*36 + p) << 9) + c*16));
    *(uint4*)((char*)Il + img*20144 + p*544 + c*16) = v;
  }

  int Abase;
  {
    int img = n >> 2, pos = n & 3;
    int py = pos >> 1, px = pos & 1;
    Abase = img*20144 + (py*6 + px)*544 + g*16;       // bytes
  }

  floatx4 acc[4];
#pragma unroll
  for (int nt = 0; nt < 4; ++nt) acc[nt] = (floatx4){0.f, 0.f, 0.f, 0.f};

  __syncthreads();   // the ONLY barrier

  int s = 0;
#pragma unroll 1
  for (int ky = 0; ky < 5; ++ky) {
#pragma unroll 1
    for (int kx = 0; kx < 5; ++kx) {
      const int tapoff = (ky*6 + kx) * 544;  // pixel offset bytes
#pragma unroll
      for (int ip = 0; ip < 4; ++ip) {
        const int scur = s + ip;
        const char* ap = (const char*)Il + Abase + tapoff + ip*128;
        bhalf8 a0 = *(const bhalf8*)(ap);
        bhalf8 a1 = *(const bhalf8*)(ap + 64);
#pragma unroll
        for (int nt = 0; nt < 4; ++nt) {
          acc[nt] = __builtin_amdgcn_mfma_f32_16x16x32_bf16(
              a0, bb[ip & 1][nt][0], acc[nt], 0, 0, 0);
          acc[nt] = __builtin_amdgcn_mfma_f32_16x16x32_bf16(
              a1, bb[ip & 1][nt][1], acc[nt], 0, 0, 0);
        }
        {
          const int spre = (scur + 2 <= 99) ? (scur + 2) : 98;
          const char* pB = gB + spre*128;
#pragma unroll
          for (int nt = 0; nt < 4; ++nt) {
            bb[ip & 1][nt][0] = *(const bhalf8*)(pB + nt*204800);
            bb[ip & 1][nt][1] = *(const bhalf8*)(pB + nt*204800 + 64);
          }
        }
      }
      s += 4;
    }
  }

  // ---- epilogue: row = g*4+r = (img,pos), col = n -> oc; fp32 [b][oc][4] ----
  float bv[4];
#pragma unroll
  for (int nt = 0; nt < 4; ++nt) bv[nt] = bias[w*64 + nt*16 + n];
#pragma unroll
  for (int r = 0; r < 4; ++r) {
    int m = g*4 + r;
    int img = m >> 2, pos = m & 3;
    float* op = out + (((size_t)(b0+img)*256 + w*64 + n)*4 + pos);
#pragma unroll
    for (int nt = 0; nt < 4; ++nt)
      op[nt*64] = fmaxf(acc[nt][r] + bv[nt], 0.f);
  }
}

// ============================================================================
// caps: squash -> u_hat -> 3x dynamic routing -> v_lengths + fused fc1
// ============================================================================
__global__ __launch_bounds__(256) void caps_kernel(
    const float* __restrict__ h3, const float* __restrict__ cw,
    const float* __restrict__ cb, const int* __restrict__ y,
    const float* __restrict__ fc1w, const float* __restrict__ fc1b,
    float* __restrict__ vlen, float* __restrict__ h1f)
{
  __shared__ float prim[1024];     // [64][16]
  __shared__ float uh[10240];      // [64][10][16]
  __shared__ float bij[640];
  __shared__ float cij[640];
  __shared__ float vv[160];        // [10][16]
  const int b = blockIdx.x, t = threadIdx.x;
  {
    const int cap = t >> 2, part = t & 3;
    float4 h = *(const float4*)&h3[b*1024 + cap*16 + part*4];
    float d = h.x*h.x + h.y*h.y + h.z*h.z + h.w*h.w;
    d += __shfl_xor(d, 1);
    d += __shfl_xor(d, 2);
    float sc = d / (1.f + d) / sqrtf(d + EPSF);
    float4 o4 = make_float4(h.x*sc, h.y*sc, h.z*sc, h.w*sc);
    *(float4*)&prim[cap*16 + part*4] = o4;
  }
  for (int f = t; f < 640; f += 256) bij[f] = 0.f;
  __syncthreads();
  for (int f = t; f < 10240; f += 256) {
    int i = f / 160, r = f % 160;
    int o = r >> 4, j = r & 15;
    const float* wp = cw + i*2560 + o*256 + j;   // k-stride 16
    const float* pp = prim + i*16;
    float s = 0.f;
#pragma unroll
    for (int k = 0; k < 16; ++k) s = fmaf(pp[k], wp[k*16], s);
    uh[f] = s;
  }
  __syncthreads();
  for (int r = 0; r < 3; ++r) {
    if (t < 64) {
      float e[10];
      float mx = -1e30f;
#pragma unroll
      for (int o = 0; o < 10; ++o) { e[o] = bij[t*10 + o]; mx = fmaxf(mx, e[o]); }
      float sum = 0.f;
#pragma unroll
      for (int o = 0; o < 10; ++o) { e[o] = expf(e[o] - mx); sum += e[o]; }
      float inv = 1.f / sum;
#pragma unroll
      for (int o = 0; o < 10; ++o) cij[t*10 + o] = e[o] * inv;
    }
    __syncthreads();
    if (t < 160) {
      const int o = t >> 4;
      float s = cb[t];
      for (int i = 0; i < 64; ++i) s = fmaf(cij[i*10 + o], uh[i*160 + t], s);
      float d = s*s;
      d += __shfl_xor(d, 1); d += __shfl_xor(d, 2);
      d += __shfl_xor(d, 4); d += __shfl_xor(d, 8);
      float sc = d / (1.f + d) / sqrtf(d + EPSF);
      vv[t] = s * sc;
      if (r == 2 && (t & 15) == 0)
        vlen[b*10 + o] = sqrtf(sc*sc*d + EPSF);
    }
    __syncthreads();
    if (r < 2) {
      for (int f = t; f < 640; f += 256) {
        int i = f / 10, o = f % 10;
        const float* up = &uh[i*160 + o*16];
        const float* vp = &vv[o*16];
        float a = 0.f;
#pragma unroll
        for (int j = 0; j < 16; ++j) a = fmaf(up[j], vp[j], a);
        bij[f] += a;
      }
      __syncthreads();
    }
  }
  const int yb = y[b];
  const float* vy = &vv[yb*16];
  for (int nn = t; nn < 512; nn += 256) {
    const float* wr = fc1w + nn*160 + yb*16;
    float s = fc1b[nn];
#pragma unroll
    for (int k = 0; k < 16; ++k) s = fmaf(vy[k], wr[k], s);
    h1f[b*512 + nn] = fmaxf(s, 0.f);
  }
}

// ============================================================================
// fc: out[M,N] = act(A[M,K] @ W[N,K]^T + bias). ACT: 0 = relu, 1 = sigmoid
// ============================================================================
template<int ACT>
__global__ __launch_bounds__(256) void fc_kernel(
    const float* __restrict__ A, const float* __restrict__ W,
    const float* __restrict__ bias, float* __restrict__ out,
    int M, int N, int K)
{
  __shared__ float Al[16*68];
  __shared__ float Bl[16*132];
  const int m0 = blockIdx.x * 64;
  const int n0 = blockIdx.y * 128;
  const int t  = threadIdx.x;
  const int tx = t & 15;
  const int ty = t >> 4;
  float acc[4][8];
#pragma unroll
  for (int i2 = 0; i2 < 4; ++i2)
#pragma unroll
    for (int j2 = 0; j2 < 8; ++j2) acc[i2][j2] = 0.f;
  for (int k0 = 0; k0 < K; k0 += 16) {
    __syncthreads();
    {
      int m = t >> 2, kq = (t & 3) * 4;
      float4 v = *(const float4*)&A[(m0 + m)*K + k0 + kq];
      Al[(kq+0)*68 + m] = v.x;
      Al[(kq+1)*68 + m] = v.y;
      Al[(kq+2)*68 + m] = v.z;
      Al[(kq+3)*68 + m] = v.w;
    }
    for (int f = t; f < 512; f += 256) {
      int nn = f >> 2, kq = (f & 3) * 4;
      float4 v = *(const float4*)&W[(n0 + nn)*K + k0 + kq];
      Bl[(kq+0)*132 + nn] = v.x;
      Bl[(kq+1)*132 + nn] = v.y;
      Bl[(kq+2)*132 + nn] = v.z;
      Bl[(kq+3)*132 + nn] = v.w;
    }
    __syncthreads();
#pragma unroll
    for (int kk = 0; kk < 16; ++kk) {
      float4 a  = *(const float4*)&Al[kk*68 + ty*4];
      float4 b0 = *(const float4*)&Bl[kk*132 + tx*8];
      float4 b1 = *(const float4*)&Bl[kk*132 + tx*8 + 4];
      float am[4] = {a.x, a.y, a.z, a.w};
      float bn[8] = {b0.x, b0.y, b0.z, b0.w, b1.x, b1.y, b1.z, b1.w};
#pragma unroll
      for (int i2 = 0; i2 < 4; ++i2)
#pragma unroll
        for (int j2 = 0; j2 < 8; ++j2)
          acc[i2][j2] = fmaf(am[i2], bn[j2], acc[i2][j2]);
    }
  }
#pragma unroll
  for (int i2 = 0; i2 < 4; ++i2) {
    const int m = m0 + ty*4 + i2;
#pragma unroll
    for (int j2 = 0; j2 < 8; ++j2) {
      const int nn = n0 + tx*8 + j2;
      float v = acc[i2][j2] + bias[nn];
      if (ACT == 0) v = fmaxf(v, 0.f);
      else          v = 1.f / (1.f + expf(-v));
      out[m*N + nn] = v;
    }
  }
}

// ============================================================================
extern "C" void kernel_launch(void* const* d_in, const int* in_sizes, int n_in,
                              void* d_out, int out_size, void* d_ws, size_t ws_size,
                              hipStream_t stream) {
  const float* x       = (const float*)d_in[0];
  const int*   y       = (const int*)  d_in[1];
  const float* conv1_w = (const float*)d_in[2];
  const float* conv1_b = (const float*)d_in[3];
  const float* conv2_w = (const float*)d_in[4];
  const float* conv2_b = (const float*)d_in[5];
  const float* conv3_w = (const float*)d_in[6];
  const float* conv3_b = (const float*)d_in[7];
  const float* caps_w  = (const float*)d_in[8];
  const float* caps_b  = (const float*)d_in[9];
  const float* fc1_w   = (const float*)d_in[10];
  const float* fc1_b   = (const float*)d_in[11];
  const float* fc2_w   = (const float*)d_in[12];
  const float* fc2_b   = (const float*)d_in[13];
  const float* fc3_w   = (const float*)d_in[14];
  const float* fc3_b   = (const float*)d_in[15];
  float* out = (float*)d_out;
  float* ws  = (float*)d_ws;

  // ws layout (float units), total 23,314,432 floats = 93.3 MB
  __hip_bfloat16* h1t = (__hip_bfloat16*)ws;                 // 29,491,200 bf16
  __hip_bfloat16* wt2 = (__hip_bfloat16*)(ws + 14745600);    //    819,200 bf16
  __hip_bfloat16* wt3 = (__hip_bfloat16*)(ws + 15155200);    //  1,638,400 bf16
  __hip_bfloat16* h2t = (__hip_bfloat16*)(ws + 15974400);    //  9,437,184 bf16
  float* h3c = ws + 20692992;      // 1,048,576
  float* h1f = ws + 21741568;      //   524,288
  float* h2f = ws + 22265856;      // 1,048,576

  wtrans_kernel <<<dim3(3200),    256, 0, stream>>>(conv2_w, wt2);
  wtrans3_kernel<<<dim3(6400),    256, 0, stream>>>(conv3_w, wt3);
  conv1_kernel<<<dim3(1024, 4),   256, 0, stream>>>(x, conv1_w, conv1_b, h1t);
  conv2_mfma_kernel<<<dim3(512),  256, 0, stream>>>(h1t, wt2, conv2_b, h2t);
  conv3_mfma_kernel<<<dim3(256),  256, 0, stream>>>(h2t, wt3, conv3_b, h3c);
  caps_kernel<<<dim3(1024),       256, 0, stream>>>(h3c, caps_w, caps_b, y,
                                                    fc1_w, fc1_b, out, h1f);
  fc_kernel<0><<<dim3(16, 8),  256, 0, stream>>>(h1f, fc2_w, fc2_b, h2f,
                                                 1024, 1024, 512);
  fc_kernel<1><<<dim3(16, 24), 256, 0, stream>>>(h2f, fc3_w, fc3_b, out + 10240,
                                                 1024, 3072, 1024);
}